// Round 1
// baseline (261.770 us; speedup 1.0000x reference)
//
#include <hip/hip_runtime.h>

#define B_ 16
#define K_ 20
#define C_ 3
#define H_ 256
#define W_ 256
#define HW_ (H_*W_)
#define RAD 4
#define TH_ 32      // output rows per strip in fused kernel (halo +8)
#define KT_ 5       // classes per stats block
#define SROWS_ 16   // rows per stats chunk

__global__ __launch_bounds__(256) void zero_ws_k(float* ws, int n) {
    int i = blockIdx.x * 256 + threadIdx.x;
    if (i < n) ws[i] = 0.f;
}

// sums layout: [4][B_*K_]: f0 = sum(l), f1..f3 = sum(l*i_c)
// grid (16 chunks, K_/KT_ tiles, B_), block 256. float4 loads; inputs loaded
// once per block and reused across KT_ classes (cuts L2/L3 input traffic 5x).
__global__ __launch_bounds__(256) void stats_k(const float* __restrict__ labels,
                                               const float* __restrict__ inputs,
                                               float* __restrict__ sums) {
    const int x = threadIdx.x;
    const int chunk = blockIdx.x;
    const int kt = blockIdx.y;
    const int b  = blockIdx.z;
    const int k0 = kt * KT_;
    const size_t cbase = (size_t)chunk * SROWS_ * W_;
    const float4* in0 = (const float4*)(inputs + (size_t)b * C_ * HW_ + cbase);
    const float4* in1 = (const float4*)(inputs + (size_t)b * C_ * HW_ + HW_ + cbase);
    const float4* in2 = (const float4*)(inputs + (size_t)b * C_ * HW_ + 2*HW_ + cbase);
    const float4* lab = (const float4*)(labels + ((size_t)(b * K_ + k0)) * HW_ + cbase);

    float4 acc[KT_][4];
#pragma unroll
    for (int kk = 0; kk < KT_; ++kk) {
#pragma unroll
        for (int f = 0; f < 4; ++f) acc[kk][f] = make_float4(0.f, 0.f, 0.f, 0.f);
    }

#define ADD4(A, L)    { (A).x += (L).x; (A).y += (L).y; (A).z += (L).z; (A).w += (L).w; }
#define FMA4(A, L, I) { (A).x = __fmaf_rn((L).x,(I).x,(A).x); (A).y = __fmaf_rn((L).y,(I).y,(A).y); \
                        (A).z = __fmaf_rn((L).z,(I).z,(A).z); (A).w = __fmaf_rn((L).w,(I).w,(A).w); }

    const int NIT = SROWS_ * W_ / 1024;   // 4 iterations of 256 threads x float4
#pragma unroll
    for (int it = 0; it < NIT; ++it) {
        const int idx = it * 256 + x;
        const float4 i0 = in0[idx];
        const float4 i1 = in1[idx];
        const float4 i2 = in2[idx];
#pragma unroll
        for (int kk = 0; kk < KT_; ++kk) {
            const float4 l = lab[(size_t)kk * (HW_ / 4) + idx];
            ADD4(acc[kk][0], l);
            FMA4(acc[kk][1], l, i0);
            FMA4(acc[kk][2], l, i1);
            FMA4(acc[kk][3], l, i2);
        }
    }

#pragma unroll
    for (int kk = 0; kk < KT_; ++kk) {
        float s0 = acc[kk][0].x + acc[kk][0].y + acc[kk][0].z + acc[kk][0].w;
        float s1 = acc[kk][1].x + acc[kk][1].y + acc[kk][1].z + acc[kk][1].w;
        float s2 = acc[kk][2].x + acc[kk][2].y + acc[kk][2].z + acc[kk][2].w;
        float s3 = acc[kk][3].x + acc[kk][3].y + acc[kk][3].z + acc[kk][3].w;
        for (int o = 32; o > 0; o >>= 1) {
            s0 += __shfl_down(s0, o); s1 += __shfl_down(s1, o);
            s2 += __shfl_down(s2, o); s3 += __shfl_down(s3, o);
        }
        if ((x & 63) == 0) {
            const int bk = b * K_ + k0 + kk;
            atomicAdd(&sums[bk],             s0);
            atomicAdd(&sums[B_*K_ + bk],     s1);
            atomicAdd(&sums[2*B_*K_ + bk],   s2);
            atomicAdd(&sums[3*B_*K_ + bk],   s3);
        }
    }
}

// Fused: weights -> separable 9x9 blur -> labels * blurred -> per-class num/den.
// grid (H_/TH_ strips, K_, B_), block 256 (one thread per column).
// Vertical pass uses a STATIC modular ring (slot = (row index)&7, inner loop
// unrolled by 8) -> no register shifting. Horizontal pass reads (w,lw) packed
// as float2 from LDS -> 9 ds_read_b64 instead of 18 ds_read_b32.
__global__ __launch_bounds__(256) void fused_k(const float* __restrict__ labels,
                                               const float* __restrict__ inputs,
                                               const float* __restrict__ sums,
                                               float* __restrict__ numden) {
    const int x = threadIdx.x;
    const int strip = blockIdx.x;
    const int k = blockIdx.y;
    const int b = blockIdx.z;
    const int bk = b * K_ + k;

    const float dn  = sums[bk] + 1e-5f * (float)HW_;
    const float cm0 = sums[B_*K_ + bk]   / dn;
    const float cm1 = sums[2*B_*K_ + bk] / dn;
    const float cm2 = sums[3*B_*K_ + bk] / dn;
    const float m2  = cm0*cm0 + cm1*cm1 + cm2*cm2;

    float g[9];
#pragma unroll
    for (int i = 0; i < 9; ++i) { float d = (float)(i - 4); g[i] = __expf(-d * d * (1.f / 50.f)); }

    __shared__ float2 sv[2][W_ + 2*RAD];
    if (x < RAD) {
        sv[0][x] = make_float2(0.f, 0.f); sv[0][W_ + RAD + x] = make_float2(0.f, 0.f);
        sv[1][x] = make_float2(0.f, 0.f); sv[1][W_ + RAD + x] = make_float2(0.f, 0.f);
    }

    const size_t lab_base = (size_t)bk * HW_;
    const size_t in_base  = (size_t)b * C_ * HW_;
    const int r0 = strip * TH_;

    // ring slot i (prologue) holds row r0-4+i; thereafter slot (rr)&7 is
    // overwritten by the row loaded at iteration rr (row r0+rr+4).
    float rw[8], rlw[8], rl[8];

    auto load_row = [&](int gr, float& w_, float& lw_, float& l_) {
        w_ = 0.f; lw_ = 0.f; l_ = 0.f;
        if ((unsigned)gr < (unsigned)H_) {
            const int off = gr * W_ + x;
            const float l  = labels[lab_base + off];
            const float i0 = inputs[in_base + off];
            const float i1 = inputs[in_base + HW_ + off];
            const float i2 = inputs[in_base + 2 * HW_ + off];
            const float df = (i0*i0 + i1*i1 + i2*i2) - 2.f * (i0*cm0 + i1*cm1 + i2*cm2) + m2;
            const float wgt = __expf(-df * df);   // SIGMA_2 = 1
            w_ = wgt; lw_ = l * wgt; l_ = l;
        }
    };

#pragma unroll
    for (int i = 0; i < 8; ++i) load_row(r0 - RAD + i, rw[i], rlw[i], rl[i]);
    __syncthreads();   // pads visible before first horizontal pass

    float num = 0.f, den = 0.f;
    for (int ro = 0; ro < TH_ / 8; ++ro) {
#pragma unroll
        for (int u = 0; u < 8; ++u) {
            const int rr = ro * 8 + u;
            float cw, clw, cl;
            load_row(r0 + rr + RAD, cw, clw, cl);
            // vertical blur: rows r0+rr-4 .. r0+rr+3 from ring, +4 from cur
            float a = 0.f, c = 0.f;
#pragma unroll
            for (int j = 0; j < 8; ++j) {
                const int s = (u + j) & 7;          // static after unroll
                a += g[j] * rw[s];
                c += g[j] * rlw[s];
            }
            a += g[8] * cw;
            c += g[8] * clw;
            const int bf = u & 1;
            sv[bf][RAD + x] = make_float2(a, c);
            __syncthreads();
            // horizontal blur
            float hw = 0.f, hlw = 0.f;
#pragma unroll
            for (int j = 0; j < 9; ++j) {
                const float2 v = sv[bf][x + j];
                hw  += g[j] * v.x;
                hlw += g[j] * v.y;
            }
            const float lc = rl[(u + 4) & 7];       // labels at the output row
            num += lc * hlw;
            den += lc * hw;
            // replace oldest ring entry (row r0+rr-4) with cur (row r0+rr+4)
            rw[u & 7] = cw; rlw[u & 7] = clw; rl[u & 7] = cl;
        }
    }

    for (int o = 32; o > 0; o >>= 1) { num += __shfl_down(num, o); den += __shfl_down(den, o); }
    __shared__ float rb[2][4];
    const int wid = x >> 6, lane = x & 63;
    __syncthreads();
    if (lane == 0) { rb[0][wid] = num; rb[1][wid] = den; }
    __syncthreads();
    if (x == 0) {
        atomicAdd(&numden[k],      rb[0][0] + rb[0][1] + rb[0][2] + rb[0][3]);
        atomicAdd(&numden[K_ + k], rb[1][0] + rb[1][1] + rb[1][2] + rb[1][3]);
    }
}

__global__ void finalize_k(const float* __restrict__ numden, float* __restrict__ out) {
    if (threadIdx.x == 0 && blockIdx.x == 0) {
        float loss = 0.f;
        for (int kk = 0; kk < K_; ++kk)
            loss += fabsf(numden[kk] / (numden[K_ + kk] + 1e-6f));
        out[0] = (float)K_ - loss;
    }
}

extern "C" void kernel_launch(void* const* d_in, const int* in_sizes, int n_in,
                              void* d_out, int out_size, void* d_ws, size_t ws_size,
                              hipStream_t stream) {
    const float* labels = (const float*)d_in[0];
    const float* inputs = (const float*)d_in[1];
    float* ws     = (float*)d_ws;
    float* sums   = ws;                 // 4 * B * K floats
    float* numden = ws + 4 * B_ * K_;   // 2 * K floats
    const int nz = 4 * B_ * K_ + 2 * K_;

    zero_ws_k<<<(nz + 255) / 256, 256, 0, stream>>>(ws, nz);
    stats_k<<<dim3(H_ / SROWS_, K_ / KT_, B_), 256, 0, stream>>>(labels, inputs, sums);
    fused_k<<<dim3(H_ / TH_, K_, B_), 256, 0, stream>>>(labels, inputs, sums, numden);
    finalize_k<<<1, 64, 0, stream>>>(numden, (float*)d_out);
}